// Round 1
// baseline (270.418 us; speedup 1.0000x reference)
//
#include <hip/hip_runtime.h>

#define KS 5
#define NORIENT 8

// ---------------- forward: stride-2 conv, 1 -> 8 channels ----------------
// out[n][c][oy][ox] = sum_{i,j} in[n][0][2oy-2+i][2ox-2+j] * f[c][i][j]
__global__ void fwd_conv_kernel(const float* __restrict__ in, long in_img_stride,
                                const float* __restrict__ filt,
                                float* __restrict__ out,
                                int H, int W, int OH, int OW, int N) {
    __shared__ float sf[NORIENT * KS * KS];
    if (threadIdx.x < NORIENT * KS * KS) sf[threadIdx.x] = filt[threadIdx.x];
    __syncthreads();

    long idx = (long)blockIdx.x * blockDim.x + threadIdx.x;
    long total = (long)N * OH * OW;
    if (idx >= total) return;
    int ox = (int)(idx % OW);
    long t = idx / OW;
    int oy = (int)(t % OH);
    int n  = (int)(t / OH);

    const float* ip = in + (long)n * in_img_stride;
    float acc[NORIENT];
#pragma unroll
    for (int c = 0; c < NORIENT; ++c) acc[c] = 0.f;

    int iy0 = 2 * oy - 2;
    int ix0 = 2 * ox - 2;
#pragma unroll
    for (int i = 0; i < KS; ++i) {
        int y = iy0 + i;
        if (y < 0 || y >= H) continue;
#pragma unroll
        for (int j = 0; j < KS; ++j) {
            int x = ix0 + j;
            if (x < 0 || x >= W) continue;
            float v = ip[(long)y * W + x];
#pragma unroll
            for (int c = 0; c < NORIENT; ++c)
                acc[c] = fmaf(v, sf[c * 25 + i * 5 + j], acc[c]);
        }
    }
    long cs = (long)OH * OW;
    long obase = (long)n * NORIENT * cs + (long)oy * OW + ox;
#pragma unroll
    for (int c = 0; c < NORIENT; ++c)
        out[obase + (long)c * cs] = acc[c];
}

// ---------------- inverse: transposed conv, 8 -> 1 channel ----------------
// out size 2h x 2w; tap (i,j) active when u=y+i-2 even, p=u/2 in [0,h)
// weight = inv_f[c][4-i][4-j] (flip), channel 0 comes from `rec`, 1..7 from `coef`.
__global__ void inv_tconv_kernel(const float* __restrict__ rec, long rec_img_stride,
                                 const float* __restrict__ coef,
                                 const float* __restrict__ filt,
                                 float* __restrict__ out,
                                 int h, int w, int N) {
    __shared__ float sf[NORIENT * KS * KS];  // pre-flipped
    if (threadIdx.x < NORIENT * KS * KS) {
        int c = threadIdx.x / 25, r = threadIdx.x % 25;
        int i = r / 5, j = r % 5;
        sf[threadIdx.x] = filt[c * 25 + (4 - i) * 5 + (4 - j)];
    }
    __syncthreads();

    int OH = 2 * h, OW = 2 * w;
    long idx = (long)blockIdx.x * blockDim.x + threadIdx.x;
    long total = (long)N * OH * OW;
    if (idx >= total) return;
    int x = (int)(idx % OW);
    long t = idx / OW;
    int y = (int)(t % OH);
    int n = (int)(t / OH);

    const float* rp = rec + (long)n * rec_img_stride;
    const float* cp = coef + (long)n * NORIENT * h * w;
    long cs = (long)h * w;

    float acc = 0.f;
#pragma unroll
    for (int i = 0; i < KS; ++i) {
        int u = y + i - 2;
        if (u & 1) continue;           // need even (negative odd also skipped)
        int p = u >> 1;
        if (p < 0 || p >= h) continue;
#pragma unroll
        for (int j = 0; j < KS; ++j) {
            int v = x + j - 2;
            if (v & 1) continue;
            int q = v >> 1;
            if (q < 0 || q >= w) continue;
            long off = (long)p * w + q;
            acc = fmaf(rp[off], sf[0 * 25 + i * 5 + j], acc);
#pragma unroll
            for (int c = 1; c < NORIENT; ++c)
                acc = fmaf(cp[(long)c * cs + off], sf[c * 25 + i * 5 + j], acc);
        }
    }
    out[(long)n * OH * OW + (long)y * OW + x] = acc;
}

extern "C" void kernel_launch(void* const* d_in, const int* in_sizes, int n_in,
                              void* d_out, int out_size, void* d_ws, size_t ws_size,
                              hipStream_t stream) {
    const float* x     = (const float*)d_in[0];
    const float* fwd_f = (const float*)d_in[1];
    const float* inv_f = (const float*)d_in[2];
    float* out = (float*)d_out;
    float* ws  = (float*)d_ws;

    const int N = 32;

    // workspace layout (floats)
    float* l4 = ws;                  // 32*8*256*256 = 16,777,216
    float* l3 = l4 + 16777216;       // 32*8*128*128 =  4,194,304
    float* l2 = l3 + 4194304;        // 32*8*64*64   =  1,048,576
    float* l1 = l2 + 1048576;        // 32*8*32*32   =    262,144
    float* r1 = l1 + 262144;         // 32*64*64     =    131,072
    float* r2 = r1 + 131072;         // 32*128*128   =    524,288
    float* r3 = r2 + 524288;         // 32*256*256   =  2,097,152
    // total = 25,034,752 floats ~ 100.1 MB

    dim3 blk(256);
    auto nblocks = [](long total) { return dim3((unsigned)((total + 255) / 256)); };

    // ---- forward transform ----
    fwd_conv_kernel<<<nblocks(32L * 256 * 256), blk, 0, stream>>>(
        x, 512L * 512, fwd_f, l4, 512, 512, 256, 256, N);
    fwd_conv_kernel<<<nblocks(32L * 128 * 128), blk, 0, stream>>>(
        l4, 8L * 256 * 256, fwd_f, l3, 256, 256, 128, 128, N);
    fwd_conv_kernel<<<nblocks(32L * 64 * 64), blk, 0, stream>>>(
        l3, 8L * 128 * 128, fwd_f, l2, 128, 128, 64, 64, N);
    fwd_conv_kernel<<<nblocks(32L * 32 * 32), blk, 0, stream>>>(
        l2, 8L * 64 * 64, fwd_f, l1, 64, 64, 32, 32, N);

    // ---- inverse transform ----
    // level 1: "full" == l1 exactly (coeffs[0] is l1 channel 0)
    inv_tconv_kernel<<<nblocks(32L * 64 * 64), blk, 0, stream>>>(
        l1, 8L * 32 * 32, l1, inv_f, r1, 32, 32, N);
    inv_tconv_kernel<<<nblocks(32L * 128 * 128), blk, 0, stream>>>(
        r1, 64L * 64, l2, inv_f, r2, 64, 64, N);
    inv_tconv_kernel<<<nblocks(32L * 256 * 256), blk, 0, stream>>>(
        r2, 128L * 128, l3, inv_f, r3, 128, 128, N);
    inv_tconv_kernel<<<nblocks(32L * 512 * 512), blk, 0, stream>>>(
        r3, 256L * 256, l4, inv_f, out, 256, 256, N);
}

// Round 2
// 119.467 us; speedup vs baseline: 2.2635x; 2.2635x over previous
//
#include <hip/hip_runtime.h>

#define NORIENT 8

// ---------------- forward: stride-2 5x5 conv, 1 -> 8 channels ----------------
// One thread computes a 2x2 output block for all 8 channels from a 7x7 patch.
// out[n][c][oy][ox] = sum_{i,j} in[n][0][2oy-2+i][2ox-2+j] * f[c][i][j]
__global__ void fwd_conv_kernel(const float* __restrict__ in, long in_img_stride,
                                const float* __restrict__ filt,
                                float* __restrict__ out,
                                int H, int W, int OH, int OW, int N) {
    int OH2 = OH >> 1, OW2 = OW >> 1;
    long idx = (long)blockIdx.x * blockDim.x + threadIdx.x;
    long total = (long)N * OH2 * OW2;
    if (idx >= total) return;
    int ox2 = (int)(idx % OW2);
    long t = idx / OW2;
    int oy2 = (int)(t % OH2);
    int n = (int)(t / OH2);

    const float* __restrict__ ip = in + (long)n * in_img_stride;
    int y0 = 4 * oy2 - 2, x0 = 4 * ox2 - 2;

    // 7x7 register patch, borders zeroed via clamp+select (branch-free)
    float patch[7][7];
#pragma unroll
    for (int i = 0; i < 7; ++i) {
        int y = y0 + i;
        bool vy = (y >= 0) & (y < H);
        const float* rowp = ip + (long)(vy ? y : 0) * W;
#pragma unroll
        for (int j = 0; j < 7; ++j) {
            int x = x0 + j;
            bool vx = (x >= 0) & (x < W);
            float v = rowp[vx ? x : 0];
            patch[i][j] = (vy & vx) ? v : 0.f;
        }
    }

    long cs = (long)OH * OW;
    long ob0 = (long)n * NORIENT * cs + (long)(2 * oy2) * OW + 2 * ox2;
#pragma unroll
    for (int c = 0; c < NORIENT; ++c) {
        const float* __restrict__ F = filt + c * 25;  // wave-uniform -> s_load
        float a00 = 0.f, a01 = 0.f, a10 = 0.f, a11 = 0.f;
#pragma unroll
        for (int i = 0; i < 5; ++i) {
#pragma unroll
            for (int j = 0; j < 5; ++j) {
                float wv = F[i * 5 + j];
                a00 = fmaf(patch[i][j],         wv, a00);
                a01 = fmaf(patch[i][j + 2],     wv, a01);
                a10 = fmaf(patch[i + 2][j],     wv, a10);
                a11 = fmaf(patch[i + 2][j + 2], wv, a11);
            }
        }
        long ob = ob0 + (long)c * cs;
        *(float2*)&out[ob]      = make_float2(a00, a01);
        *(float2*)&out[ob + OW] = make_float2(a10, a11);
    }
}

// ---------------- inverse: transposed conv, 8 -> 1 channel, stride 2 ----------------
// Polyphase: thread owns coeff site (p,q), computes the 2x2 output block
// (2p..2p+1, 2q..2q+1) from a 3x3 patch per channel. Each of the 25 weights
// has fixed tap parity -> feeds exactly one of the 4 outputs. Branch-free.
__global__ void inv_tconv_kernel(const float* __restrict__ rec, long rec_img_stride,
                                 const float* __restrict__ coef,
                                 const float* __restrict__ filt,
                                 float* __restrict__ out,
                                 int h, int w, int N) {
    long idx = (long)blockIdx.x * blockDim.x + threadIdx.x;
    long total = (long)N * h * w;
    if (idx >= total) return;
    int q = (int)(idx % w);
    long t = idx / w;
    int p = (int)(t % h);
    int n = (int)(t / h);

    const float* __restrict__ rp = rec + (long)n * rec_img_stride;
    const float* __restrict__ cp = coef + (long)n * NORIENT * h * w;
    int cs = h * w;

    int off = p * w + q;
    bool vm = p > 0, vp = p < h - 1, um = q > 0, up = q < w - 1;
    int dm = um ? -1 : 0;
    int dp = up ? 1 : 0;
    int om = vm ? off - w : off;
    int op = vp ? off + w : off;

    // combined masks (center row/col mask = 1)
    float m00 = (vm & um) ? 1.f : 0.f, m01 = vm ? 1.f : 0.f, m02 = (vm & up) ? 1.f : 0.f;
    float m10 = um ? 1.f : 0.f,                               m12 = up ? 1.f : 0.f;
    float m20 = (vp & um) ? 1.f : 0.f, m21 = vp ? 1.f : 0.f, m22 = (vp & up) ? 1.f : 0.f;

    float o00 = 0.f, o01 = 0.f, o10 = 0.f, o11 = 0.f;

#pragma unroll
    for (int c = 0; c < NORIENT; ++c) {
        const float* __restrict__ src = (c == 0) ? rp : (cp + c * cs);
        const float* __restrict__ F = filt + c * 25;  // wave-uniform -> s_load

        float v[3][3];
        v[0][0] = src[om + dm]  * m00;
        v[0][1] = src[om]       * m01;
        v[0][2] = src[om + dp]  * m02;
        v[1][0] = src[off + dm] * m10;
        v[1][1] = src[off];
        v[1][2] = src[off + dp] * m12;
        v[2][0] = src[op + dm]  * m20;
        v[2][1] = src[op]       * m21;
        v[2][2] = src[op + dp]  * m22;

        // weights already account for the flip: sf[i][j] = filt[4-i][4-j]
#pragma unroll
        for (int a = 0; a < 3; ++a) {
#pragma unroll
            for (int b = 0; b < 3; ++b) {
                o00 = fmaf(v[a][b], F[(4 - 2 * a) * 5 + (4 - 2 * b)], o00);
                if (b >= 1) o01 = fmaf(v[a][b], F[(4 - 2 * a) * 5 + (5 - 2 * b)], o01);
                if (a >= 1) o10 = fmaf(v[a][b], F[(5 - 2 * a) * 5 + (4 - 2 * b)], o10);
                if (a >= 1 && b >= 1)
                            o11 = fmaf(v[a][b], F[(5 - 2 * a) * 5 + (5 - 2 * b)], o11);
            }
        }
    }

    int OW = 2 * w;
    long ob = (long)n * 4 * cs + (long)(2 * p) * OW + 2 * q;
    *(float2*)&out[ob]      = make_float2(o00, o01);
    *(float2*)&out[ob + OW] = make_float2(o10, o11);
}

extern "C" void kernel_launch(void* const* d_in, const int* in_sizes, int n_in,
                              void* d_out, int out_size, void* d_ws, size_t ws_size,
                              hipStream_t stream) {
    const float* x     = (const float*)d_in[0];
    const float* fwd_f = (const float*)d_in[1];
    const float* inv_f = (const float*)d_in[2];
    float* out = (float*)d_out;
    float* ws  = (float*)d_ws;

    const int N = 32;

    // workspace layout (floats)
    float* l4 = ws;                  // 32*8*256*256 = 16,777,216
    float* l3 = l4 + 16777216;       // 32*8*128*128 =  4,194,304
    float* l2 = l3 + 4194304;        // 32*8*64*64   =  1,048,576
    float* l1 = l2 + 1048576;        // 32*8*32*32   =    262,144
    float* r1 = l1 + 262144;         // 32*64*64     =    131,072
    float* r2 = r1 + 131072;         // 32*128*128   =    524,288
    float* r3 = r2 + 524288;         // 32*256*256   =  2,097,152

    dim3 blk(256);
    auto nblocks = [](long total) { return dim3((unsigned)((total + 255) / 256)); };

    // ---- forward transform (threads = N * OH/2 * OW/2) ----
    fwd_conv_kernel<<<nblocks(32L * 128 * 128), blk, 0, stream>>>(
        x, 512L * 512, fwd_f, l4, 512, 512, 256, 256, N);
    fwd_conv_kernel<<<nblocks(32L * 64 * 64), blk, 0, stream>>>(
        l4, 8L * 256 * 256, fwd_f, l3, 256, 256, 128, 128, N);
    fwd_conv_kernel<<<nblocks(32L * 32 * 32), blk, 0, stream>>>(
        l3, 8L * 128 * 128, fwd_f, l2, 128, 128, 64, 64, N);
    fwd_conv_kernel<<<nblocks(32L * 16 * 16), blk, 0, stream>>>(
        l2, 8L * 64 * 64, fwd_f, l1, 64, 64, 32, 32, N);

    // ---- inverse transform (threads = N * h * w) ----
    inv_tconv_kernel<<<nblocks(32L * 32 * 32), blk, 0, stream>>>(
        l1, 8L * 32 * 32, l1, inv_f, r1, 32, 32, N);
    inv_tconv_kernel<<<nblocks(32L * 64 * 64), blk, 0, stream>>>(
        r1, 64L * 64, l2, inv_f, r2, 64, 64, N);
    inv_tconv_kernel<<<nblocks(32L * 128 * 128), blk, 0, stream>>>(
        r2, 128L * 128, l3, inv_f, r3, 128, 128, N);
    inv_tconv_kernel<<<nblocks(32L * 256 * 256), blk, 0, stream>>>(
        r3, 256L * 256, l4, inv_f, out, 256, 256, N);
}